// Round 8
// baseline (243.537 us; speedup 1.0000x reference)
//
#include <hip/hip_runtime.h>

// FeedForwardQuantum fused: out = q(x@w1^T + b1) @ w2^T + b2
// Quantum layer reduced analytically (Clifford circuit):
//   c_i = cos(h_i); q_f = parity-chain prefix products of c_i;
//   q7 = (even chain)*(odd chain).
//
// Round 8 = Round 7 resubmitted (container failed twice; no data).
// Wave-private double-buffered DMA pipeline (T3/T4):
//   R6 proved global_load_lds staging moves the needle (86->79us) but
//   drained vmcnt(0) once per block, exposing the full HBM round-trip.
//   Here: block owns 16 rows = 4 chunks x 4 rows, LDS double-buffered.
//   Steady state per wave: stage(c+1) -> s_waitcnt vmcnt(4) -> compute
//   chunk c. Counted vmcnt, never 0 in the loop (T4); each wave consumes
//   only bytes it staged itself -> ZERO barriers in the pipeline. One
//   barrier pair at the end for the cross-wave partial combine.
//   Compute phases bit-identical to verified R4/R6 DPP code.
//   No hang hazard: s_waitcnt waits on a count (always drains), barriers
//   are reached unconditionally by all threads.

typedef float f4 __attribute__((ext_vector_type(4)));

constexpr int THREADS = 256;
constexpr int CR      = 4;            // rows per chunk
constexpr int NC      = 4;            // chunks per block
constexpr int BR      = CR * NC;      // 16 rows per block -> 2048 blocks
constexpr int E       = 1024;
constexpr int R_TOTAL = 8 * 4096;     // 32768 rows

template<int CTRL>
__device__ __forceinline__ float dppf(float v) {
    // update_dpp: old=0, row_mask=0xF, bank_mask=0xF, bound_ctrl=true.
    return __int_as_float(__builtin_amdgcn_update_dpp(
        0, __float_as_int(v), CTRL, 0xF, 0xF, true));
}
// DPP ctrl encodings (gfx9): quad_perm[1,0,3,2]=0xB1 (xor1),
// quad_perm[2,3,0,1]=0x4E (xor2), row_ror:4=0x124, row_ror:8=0x128.

// Stage one 4-row chunk: wave wid DMAs its quarter of each row.
// LDS dest is wave-uniform; HW adds lane*16B. Global src is per-lane.
__device__ __forceinline__ void stage_chunk(const float* __restrict__ x,
                                            float* lds_buf,
                                            int row0, int chunk,
                                            int wid, int lane)
{
#pragma unroll
    for (int r = 0; r < CR; ++r) {
        __builtin_amdgcn_global_load_lds(
            (const __attribute__((address_space(1))) void*)
                (x + (size_t)(row0 + chunk * CR + r) * E + wid * 256 + lane * 4),
            (__attribute__((address_space(3))) void*)
                (lds_buf + r * E + wid * 256),
            16, 0, 0);
    }
}

__global__ __launch_bounds__(THREADS, 4)
void ffq_kernel(const float* __restrict__ x,
                const float* __restrict__ w1,
                const float* __restrict__ b1,
                const float* __restrict__ w2,
                const float* __restrict__ b2,
                float* __restrict__ out)
{
    __shared__ __align__(16) float lds_x[2][CR * E];   // 2 x 16 KB dbuf
    __shared__ float part[BR * 16 * 9];                // 9.2 KB partials
    __shared__ __align__(16) float qsh[BR][8];
    __shared__ float b1s[8];

    const int t    = threadIdx.x;
    const int lane = t & 63;
    const int wid  = t >> 6;
    const int c0   = t * 4;           // this thread's 4 columns of E

    const int row0 = blockIdx.x * BR;

    // Oldest VMEM ops: w1/b1 register loads (drained by the first counted
    // waitcnt, ordered ahead of all stage DMAs in the vmcnt FIFO).
    if (t < 8) b1s[t] = b1[t];
    f4 w1r[8];
#pragma unroll
    for (int f = 0; f < 8; ++f)
        w1r[f] = *(const f4*)(w1 + f * E + c0);

    // LDS-writer bookkeeping: after ror4+ror8 every lane holds its
    // {bit2,bit3}-coset sum; lanes with (lane&12)==0 write the 4 per-wave
    // partials jj = wid*4 + (lane>>4), features lane&3 and (lane&3)+4.
    const bool writer = (lane & 12) == 0;
    const int  jj     = wid * 4 + (lane >> 4);   // 0..15
    const int  fb     = lane & 3;

    // ---- prologue: stage chunk 0 ----
    stage_chunk(x, &lds_x[0][0], row0, 0, wid, lane);

    // ---- pipelined phase 1: stage(c+1) || compute(c), counted vmcnt ----
#pragma unroll
    for (int c = 0; c < NC; ++c) {
        const int buf = c & 1;

        if (c + 1 < NC) {
            stage_chunk(x, &lds_x[buf ^ 1][0], row0, c + 1, wid, lane);
            // chunk c's 4 DMAs complete; chunk c+1's 4 stay in flight.
            asm volatile("s_waitcnt vmcnt(4)" ::: "memory");
        } else {
            asm volatile("s_waitcnt vmcnt(0)" ::: "memory");
        }

#pragma unroll
        for (int s = 0; s < CR; ++s) {
            const int rb = c * CR + s;            // row within block
            const f4 xc = *(const f4*)(&lds_x[buf][s * E + t * 4]);

            float h[8];
#pragma unroll
            for (int f = 0; f < 8; ++f)
                h[f] = xc.x * w1r[f].x + xc.y * w1r[f].y
                     + xc.z * w1r[f].z + xc.w * w1r[f].w;

            // merge xor1 (keep features with f&1 == lane&1)
            {
                const bool hb = lane & 1;
                float s0 = hb ? h[0] : h[1];
                float s1 = hb ? h[2] : h[3];
                float s2 = hb ? h[4] : h[5];
                float s3 = hb ? h[6] : h[7];
                s0 = dppf<0xB1>(s0); s1 = dppf<0xB1>(s1);
                s2 = dppf<0xB1>(s2); s3 = dppf<0xB1>(s3);
                h[0] = (hb ? h[1] : h[0]) + s0;   // feature 0+b0
                h[1] = (hb ? h[3] : h[2]) + s1;   // feature 2+b0
                h[2] = (hb ? h[5] : h[4]) + s2;   // feature 4+b0
                h[3] = (hb ? h[7] : h[6]) + s3;   // feature 6+b0
            }
            // merge xor2 (keep features with f&2 == lane&2)
            float v0, v1;
            {
                const bool hb = lane & 2;
                float s0 = hb ? h[0] : h[1];
                float s1 = hb ? h[2] : h[3];
                s0 = dppf<0x4E>(s0); s1 = dppf<0x4E>(s1);
                v0 = (hb ? h[1] : h[0]) + s0;     // feature lane&3
                v1 = (hb ? h[3] : h[2]) + s1;     // feature (lane&3)+4
            }
            // reduce lane bits {2,3}: rotate-reduce within 16-lane row
            v0 += dppf<0x124>(v0);  v1 += dppf<0x124>(v1);   // row_ror:4
            v0 += dppf<0x128>(v0);  v1 += dppf<0x128>(v1);   // row_ror:8

            // defer bits {4,5} + cross-wave: fire-and-forget LDS partials
            if (writer) {
                const int w = (rb * 16 + jj) * 9 + fb;
                part[w]     = v0;
                part[w + 4] = v1;
            }
        }
    }
    __syncthreads();   // barrier 1 of 2 (cross-wave partial combine)

    // ------------- phase 2: sum partials, cos, prefix (t<128) -------------
    if (t < BR * 8) {
        const int r = t >> 3;
        const int f = t & 7;
        float hq = b1s[f];
#pragma unroll
        for (int j = 0; j < 16; ++j)
            hq += part[(r * 16 + j) * 9 + f];
        float p = __cosf(hq);
        float u = __shfl_up(p, 2, 8); if (f >= 2) p *= u;
        u = __shfl_up(p, 4, 8);       if (f >= 4) p *= u;
        const float p6 = __shfl(p, 6, 8);   // even-chain full product
        if (f == 7) p *= p6;
        qsh[r][f] = p;
    }

    // w2/b2 register loads: latency overlaps phase 2 + barrier; w1r dead.
    float w2a[4][8];
#pragma unroll
    for (int j = 0; j < 4; ++j) {
        const f4 lo = *(const f4*)(w2 + (size_t)(c0 + j) * 8);
        const f4 hi = *(const f4*)(w2 + (size_t)(c0 + j) * 8 + 4);
        w2a[j][0] = lo.x; w2a[j][1] = lo.y; w2a[j][2] = lo.z; w2a[j][3] = lo.w;
        w2a[j][4] = hi.x; w2a[j][5] = hi.y; w2a[j][6] = hi.z; w2a[j][7] = hi.w;
    }
    const f4 b2v = *(const f4*)(b2 + c0);

    __syncthreads();   // barrier 2 of 2

    // ---------------- phase 3: out = q @ w2^T + b2 ----------------
    // nt-stores keep out from evicting x's L3 footprint (FETCH shows half
    // of x rides L3 -> keep protecting it).
#pragma unroll
    for (int s = 0; s < BR; ++s) {
        const f4 qlo = *(const f4*)(&qsh[s][0]);   // broadcast reads
        const f4 qhi = *(const f4*)(&qsh[s][4]);
        const float qv[8] = {qlo.x, qlo.y, qlo.z, qlo.w,
                             qhi.x, qhi.y, qhi.z, qhi.w};
        f4 o = b2v;
#pragma unroll
        for (int f = 0; f < 8; ++f) {
            o.x += qv[f] * w2a[0][f];
            o.y += qv[f] * w2a[1][f];
            o.z += qv[f] * w2a[2][f];
            o.w += qv[f] * w2a[3][f];
        }
        __builtin_nontemporal_store(o, (f4*)(out + (size_t)(row0 + s) * E + c0));
    }
}

extern "C" void kernel_launch(void* const* d_in, const int* in_sizes, int n_in,
                              void* d_out, int out_size, void* d_ws, size_t ws_size,
                              hipStream_t stream)
{
    const float* x  = (const float*)d_in[0];
    const float* w1 = (const float*)d_in[1];
    const float* b1 = (const float*)d_in[2];
    const float* w2 = (const float*)d_in[3];
    const float* b2 = (const float*)d_in[4];
    float* out = (float*)d_out;

    ffq_kernel<<<dim3(R_TOTAL / BR), THREADS, 0, stream>>>(x, w1, b1, w2, b2, out);
}